// Round 11
// baseline (295.847 us; speedup 1.0000x reference)
//
#include <hip/hip_runtime.h>
#include <hip/hip_fp16.h>

#define N_NODES 100000
#define N_EDGES 1600000
#define NB 391            // buckets = dst>>8 (256 nodes each)
#define CHUNK 6250        // N_EDGES / 256 exactly
#define NBLK 256          // partition blocks
#define BPAD 4736         // padded per-bucket stride
#define GB1 1563          // gemm1 blocks = ceil(N/64)

typedef _Float16 half8 __attribute__((ext_vector_type(8)));
typedef float f32x4 __attribute__((ext_vector_type(4)));

static __device__ __forceinline__ unsigned pkh2(float a, float b) {
    __half2 t = __floats2half2_rn(a, b);
    return *(unsigned*)&t;
}

static __device__ __forceinline__ __half2 shfl_xor_h2(__half2 v, int off) {
    int t = __shfl_xor(*(int*)&v, off);
    return *(__half2*)&t;
}

// ======================= gemm1 body (MFMA, sliced-h output) =================
// h output layout: hs[head][node][32] fp16 (head = col/32).
static __device__ void gemm1_body(
    int blk, char* smem,
    const float* __restrict__ x, const float* __restrict__ W,
    const float* __restrict__ al, const float* __restrict__ ar,
    _Float16* __restrict__ hs, float* __restrict__ el, float* __restrict__ er)
{
    _Float16* Wt = (_Float16*)smem;            // [col][k] 128x136
    _Float16* xs = (_Float16*)(smem + 34816);  // [row][k] 64x136, then C
    const int tid = threadIdx.x;
    const int n0 = blk * 64;

    #pragma unroll
    for (int pass = 0; pass < 16; ++pass) {
        int k  = (tid >> 5) + pass * 8;
        int c4 = (tid & 31) * 4;
        float4 w = *(const float4*)(W + (size_t)k * 128 + c4);
        Wt[(c4 + 0) * 136 + k] = (_Float16)w.x;
        Wt[(c4 + 1) * 136 + k] = (_Float16)w.y;
        Wt[(c4 + 2) * 136 + k] = (_Float16)w.z;
        Wt[(c4 + 3) * 136 + k] = (_Float16)w.w;
    }
    {
        int row = tid >> 2, kq = (tid & 3) * 32;
        int n = n0 + row;
        _Float16* d = xs + row * 136 + kq;
        if (n < N_NODES) {
            const float* xp = x + (size_t)n * 128 + kq;
            #pragma unroll
            for (int j = 0; j < 8; ++j) {
                float4 v = *(const float4*)(xp + j * 4);
                d[j*4+0] = (_Float16)v.x; d[j*4+1] = (_Float16)v.y;
                d[j*4+2] = (_Float16)v.z; d[j*4+3] = (_Float16)v.w;
            }
        } else {
            #pragma unroll
            for (int j = 0; j < 32; ++j) d[j] = (_Float16)0.f;
        }
    }
    __syncthreads();

    const int wv = tid >> 6, l = tid & 63;
    const int r0 = wv * 16;
    const int lc = l & 15, lk = l >> 4;

    half8 afr[4];
    #pragma unroll
    for (int ks = 0; ks < 4; ++ks)
        afr[ks] = *(const half8*)(xs + (r0 + lc) * 136 + ks * 32 + lk * 8);
    __syncthreads();

    float eh_l[4][4], eh_r[4][4];
    #pragma unroll
    for (int hd = 0; hd < 4; ++hd)
        #pragma unroll
        for (int i = 0; i < 4; ++i) { eh_l[hd][i] = 0.f; eh_r[hd][i] = 0.f; }

    f32x4 accs[8];
    #pragma unroll
    for (int ct = 0; ct < 8; ++ct) {
        f32x4 acc = {0.f, 0.f, 0.f, 0.f};
        #pragma unroll
        for (int ks = 0; ks < 4; ++ks) {
            half8 b = *(const half8*)(Wt + (ct * 16 + lc) * 136 + ks * 32 + lk * 8);
            acc = __builtin_amdgcn_mfma_f32_16x16x32_f16(afr[ks], b, acc, 0, 0, 0);
        }
        accs[ct] = acc;
        float a_l = al[ct * 16 + lc], a_r = ar[ct * 16 + lc];
        #pragma unroll
        for (int i = 0; i < 4; ++i) {
            eh_l[ct >> 1][i] = fmaf(acc[i], a_l, eh_l[ct >> 1][i]);
            eh_r[ct >> 1][i] = fmaf(acc[i], a_r, eh_r[ct >> 1][i]);
        }
    }

    #pragma unroll
    for (int ct = 0; ct < 8; ++ct)
        #pragma unroll
        for (int i = 0; i < 4; ++i)
            xs[(r0 + lk * 4 + i) * 136 + ct * 16 + lc] = (_Float16)accs[ct][i];

    #pragma unroll
    for (int hd = 0; hd < 4; ++hd)
        #pragma unroll
        for (int i = 0; i < 4; ++i) {
            float v = eh_l[hd][i];
            v += __shfl_xor(v, 1); v += __shfl_xor(v, 2);
            v += __shfl_xor(v, 4); v += __shfl_xor(v, 8);
            eh_l[hd][i] = v;
            float u = eh_r[hd][i];
            u += __shfl_xor(u, 1); u += __shfl_xor(u, 2);
            u += __shfl_xor(u, 4); u += __shfl_xor(u, 8);
            eh_r[hd][i] = u;
        }
    if (lc == 0) {
        #pragma unroll
        for (int i = 0; i < 4; ++i) {
            int n = n0 + r0 + lk * 4 + i;
            if (n < N_NODES) {
                #pragma unroll
                for (int hd = 0; hd < 4; ++hd) {
                    el[n * 4 + hd] = eh_l[hd][i];
                    er[n * 4 + hd] = eh_r[hd][i];
                }
            }
        }
    }
    __syncthreads();
    // store sliced: thread (row, idx) writes cols [idx*32, idx*32+32) of its row
    {
        int row = tid >> 2, idx = tid & 3;
        int n = n0 + row;
        if (n < N_NODES) {
            _Float16* dp = hs + ((size_t)idx * N_NODES + n) * 32;
            const _Float16* sp = xs + row * 136 + idx * 32;
            #pragma unroll
            for (int j = 0; j < 4; ++j)
                *(uint4*)(dp + j * 8) = *(const uint4*)(sp + j * 8);
        }
    }
}

// ======================= csr body (one block per bucket) ====================
static __device__ void csr_body(
    int b, char* smem,
    const unsigned* __restrict__ pairs, const int* __restrict__ cursor,
    unsigned* __restrict__ rowdeg, int* __restrict__ csr_src)
{
    int* cnt = (int*)smem;
    int* exc = (int*)(smem + 1024);
    const int tid = threadIdx.x;
    cnt[tid] = 0;
    __syncthreads();
    int beg = b * BPAD;
    int end = beg + cursor[b];
    for (int i = beg + tid; i < end; i += 256)
        atomicAdd(&cnt[pairs[i] >> 17], 1);
    __syncthreads();
    int v = cnt[tid];
    exc[tid] = v;
    __syncthreads();
    for (int o = 1; o < 256; o <<= 1) {
        int t = (tid >= o) ? exc[tid - o] : 0;
        __syncthreads();
        exc[tid] += t;
        __syncthreads();
    }
    int excl = exc[tid] - v;
    int node = b * 256 + tid;
    if (node < N_NODES)
        rowdeg[node] = ((unsigned)(beg + excl) << 8) | (unsigned)v;
    __syncthreads();
    exc[tid] = beg + excl;
    cnt[tid] = 0;
    __syncthreads();
    for (int i = beg + tid; i < end; i += 256) {
        unsigned e = pairs[i];
        int dl = (int)(e >> 17);
        int r = atomicAdd(&cnt[dl], 1);
        csr_src[exc[dl] + r] = (int)(e & 0x1FFFFu);
    }
}

// ---- merged launch: csr buckets (blocks 0..NB) + gemm1 (blocks NB..NB+GB1) --
__global__ __launch_bounds__(256) void k_mix1(
    const float* __restrict__ x, const float* __restrict__ W,
    const float* __restrict__ al, const float* __restrict__ ar,
    _Float16* __restrict__ hs, float* __restrict__ el, float* __restrict__ er,
    const unsigned* __restrict__ pairs, const int* __restrict__ cursor,
    unsigned* __restrict__ rowdeg, int* __restrict__ csr_src)
{
    __shared__ __align__(16) char smem[52224];
    if (blockIdx.x < NB)
        csr_body(blockIdx.x, smem, pairs, cursor, rowdeg, csr_src);
    else
        gemm1_body(blockIdx.x - NB, smem, x, W, al, ar, hs, el, er);
}

// ===== layer 2 GEMM (MFMA): h2 = selu(out1) @ W2 (K=128, N=64) =====
__global__ __launch_bounds__(256) void k_gemm2(
    const __half* __restrict__ in, const float* __restrict__ W,
    const float* __restrict__ al, const float* __restrict__ ar,
    __half* __restrict__ h, float* __restrict__ el, float* __restrict__ er)
{
    __shared__ _Float16 Wt[64 * 136];   // [col][k]
    __shared__ _Float16 xs[64 * 136];   // [row][k], then C
    const int tid = threadIdx.x;
    const int n0 = blockIdx.x * 64;
    const float SC = 1.0507009873554805f;
    const float AL = 1.6732632423543772f;

    #pragma unroll
    for (int pass = 0; pass < 8; ++pass) {
        int k  = (tid >> 4) + pass * 16;
        int c4 = (tid & 15) * 4;
        float4 w = *(const float4*)(W + (size_t)k * 64 + c4);
        Wt[(c4 + 0) * 136 + k] = (_Float16)w.x;
        Wt[(c4 + 1) * 136 + k] = (_Float16)w.y;
        Wt[(c4 + 2) * 136 + k] = (_Float16)w.z;
        Wt[(c4 + 3) * 136 + k] = (_Float16)w.w;
    }
    {
        int row = tid >> 2, kq = (tid & 3) * 32;
        int n = n0 + row;
        _Float16* d = xs + row * 136 + kq;
        if (n < N_NODES) {
            const __half* ip = in + (size_t)n * 128 + kq;
            #pragma unroll
            for (int j = 0; j < 8; ++j) {
                uint2 u = *(const uint2*)(ip + j * 4);
                float2 f01 = __half22float2(*(__half2*)&u.x);
                float2 f23 = __half22float2(*(__half2*)&u.y);
                float v0 = f01.x > 0.f ? SC * f01.x : SC * AL * (__expf(f01.x) - 1.f);
                float v1 = f01.y > 0.f ? SC * f01.y : SC * AL * (__expf(f01.y) - 1.f);
                float v2 = f23.x > 0.f ? SC * f23.x : SC * AL * (__expf(f23.x) - 1.f);
                float v3 = f23.y > 0.f ? SC * f23.y : SC * AL * (__expf(f23.y) - 1.f);
                d[j*4+0] = (_Float16)v0; d[j*4+1] = (_Float16)v1;
                d[j*4+2] = (_Float16)v2; d[j*4+3] = (_Float16)v3;
            }
        } else {
            #pragma unroll
            for (int j = 0; j < 32; ++j) d[j] = (_Float16)0.f;
        }
    }
    __syncthreads();

    const int wv = tid >> 6, l = tid & 63;
    const int r0 = wv * 16;
    const int lc = l & 15, lk = l >> 4;

    half8 afr[4];
    #pragma unroll
    for (int ks = 0; ks < 4; ++ks)
        afr[ks] = *(const half8*)(xs + (r0 + lc) * 136 + ks * 32 + lk * 8);
    __syncthreads();

    float pl[4], pr[4];
    #pragma unroll
    for (int i = 0; i < 4; ++i) { pl[i] = 0.f; pr[i] = 0.f; }

    f32x4 accs[4];
    #pragma unroll
    for (int ct = 0; ct < 4; ++ct) {
        f32x4 acc = {0.f, 0.f, 0.f, 0.f};
        #pragma unroll
        for (int ks = 0; ks < 4; ++ks) {
            half8 b = *(const half8*)(Wt + (ct * 16 + lc) * 136 + ks * 32 + lk * 8);
            acc = __builtin_amdgcn_mfma_f32_16x16x32_f16(afr[ks], b, acc, 0, 0, 0);
        }
        accs[ct] = acc;
        float a_l = al[ct * 16 + lc], a_r = ar[ct * 16 + lc];
        #pragma unroll
        for (int i = 0; i < 4; ++i) {
            pl[i] = fmaf(acc[i], a_l, pl[i]);
            pr[i] = fmaf(acc[i], a_r, pr[i]);
        }
    }

    #pragma unroll
    for (int ct = 0; ct < 4; ++ct)
        #pragma unroll
        for (int i = 0; i < 4; ++i)
            xs[(r0 + lk * 4 + i) * 136 + ct * 16 + lc] = (_Float16)accs[ct][i];

    #pragma unroll
    for (int i = 0; i < 4; ++i) {
        float v = pl[i];
        v += __shfl_xor(v, 1); v += __shfl_xor(v, 2);
        v += __shfl_xor(v, 4); v += __shfl_xor(v, 8);
        pl[i] = v;
        float u = pr[i];
        u += __shfl_xor(u, 1); u += __shfl_xor(u, 2);
        u += __shfl_xor(u, 4); u += __shfl_xor(u, 8);
        pr[i] = u;
    }
    if (lc == 0) {
        #pragma unroll
        for (int i = 0; i < 4; ++i) {
            int n = n0 + r0 + lk * 4 + i;
            if (n < N_NODES) { el[n] = pl[i]; er[n] = pr[i]; }
        }
    }
    __syncthreads();
    {
        int row = tid >> 2, kq = (tid & 3) * 16;
        int n = n0 + row;
        if (n < N_NODES) {
            #pragma unroll
            for (int j = 0; j < 2; ++j)
                *(uint4*)(h + (size_t)n * 64 + kq + j * 8) =
                    *(const uint4*)(xs + row * 136 + kq + j * 8);
        }
    }
}

// ---- place: LDS bucket histogram -> bulk cursor reservation -> padded write ----
__global__ __launch_bounds__(256) void k_place(
    const int* __restrict__ src, const int* __restrict__ dst,
    int* __restrict__ cursor, unsigned* __restrict__ pairs)
{
    __shared__ int cnt[NB], basev[NB];
    const int tid = threadIdx.x;
    for (int j = tid; j < NB; j += 256) cnt[j] = 0;
    __syncthreads();
    int beg = blockIdx.x * CHUNK, end = beg + CHUNK;
    for (int i = beg + tid; i < end; i += 256)
        atomicAdd(&cnt[dst[i] >> 8], 1);
    __syncthreads();
    for (int j = tid; j < NB; j += 256)
        basev[j] = cnt[j] ? atomicAdd(&cursor[j], cnt[j]) : 0;
    __syncthreads();
    for (int j = tid; j < NB; j += 256) cnt[j] = 0;
    __syncthreads();
    for (int i = beg + tid; i < end; i += 256) {
        int d = dst[i];
        int b = d >> 8;
        int r = atomicAdd(&cnt[b], 1);
        pairs[(size_t)b * BPAD + basev[b] + r] =
            ((unsigned)(d & 255) << 17) | (unsigned)src[i];
    }
}

// ---- layer 1 fused attention+aggregate: one wave per (node, head) ----
// bid = chunk*4 + head: head s pinned to XCDs {s, s+4} via blockIdx round-robin.
// Gather: 64 B/edge from sliced hs[s][node][32]; 16 edges in flight per load.
__global__ __launch_bounds__(256) void k_fused1(
    const unsigned* __restrict__ rowdeg, const int* __restrict__ csr_src,
    const _Float16* __restrict__ hs,  // [4][N][32] fp16 sliced
    const float* __restrict__ el,  // [N,4]
    const float* __restrict__ er,  // [N,4]
    __half* __restrict__ out)      // [N,128] fp16 row-major
{
    __shared__ int    s_sx[4][64];
    __shared__ __half s_ph[4][64];
    const int w = threadIdx.x >> 6;
    const int lane = threadIdx.x & 63;
    const int s = blockIdx.x & 3;       // head
    const int c = blockIdx.x >> 2;      // node chunk (8 nodes)
    const int q = lane & 3, g = lane >> 2;
    const _Float16* hbase = hs + (size_t)s * N_NODES * 32;

    #pragma unroll 1
    for (int ni = 0; ni < 2; ++ni) {
        int nd = c * 8 + w * 2 + ni;
        unsigned rd = rowdeg[nd];
        int rs = (int)(rd >> 8), deg = (int)(rd & 255u);
        int re = rs + deg;
        float erd = er[nd * 4 + s];
        float m, ssum = 0.f;
        __half2 acc2[4];
        #pragma unroll
        for (int k = 0; k < 4; ++k) acc2[k] = __half2half2((__half)0.f);

        auto agg = [&](int nch) {
            int nit = (nch + 15) >> 4;
            for (int t = 0; t < nit; ++t) {
                int eb = t * 16 + g;
                int sj = s_sx[w][eb];
                __half2 a = __half2half2(s_ph[w][eb]);
                uint4 v = *((const uint4*)(hbase + (size_t)sj * 32) + q);
                acc2[0] = __hfma2(*(__half2*)&v.x, a, acc2[0]);
                acc2[1] = __hfma2(*(__half2*)&v.y, a, acc2[1]);
                acc2[2] = __hfma2(*(__half2*)&v.z, a, acc2[2]);
                acc2[3] = __hfma2(*(__half2*)&v.w, a, acc2[3]);
            }
        };

        if (deg > 0) {
            // first chunk: m = chunk max, no rescale
            int nch = min(64, deg);
            int sidx = 0;
            float e = -INFINITY;
            if (lane < nch) {
                sidx = csr_src[rs + lane];
                e = el[sidx * 4 + s] + erd;
                e = e >= 0.f ? e : 0.2f * e;
            }
            float cmx = e;
            #pragma unroll
            for (int o = 32; o > 0; o >>= 1) cmx = fmaxf(cmx, __shfl_xor(cmx, o));
            m = cmx;
            float p = __expf(e - m);
            s_sx[w][lane] = sidx;
            s_ph[w][lane] = (__half)p;
            float qq = p;
            #pragma unroll
            for (int o = 32; o > 0; o >>= 1) qq += __shfl_xor(qq, o);
            ssum = qq;
            agg(nch);

            // degree > 64 tail (never taken for this graph; kept for correctness)
            for (int base = rs + 64; base < re; base += 64) {
                nch = min(64, re - base);
                sidx = 0;
                e = -INFINITY;
                if (lane < nch) {
                    sidx = csr_src[base + lane];
                    e = el[sidx * 4 + s] + erd;
                    e = e >= 0.f ? e : 0.2f * e;
                }
                cmx = e;
                #pragma unroll
                for (int o = 32; o > 0; o >>= 1) cmx = fmaxf(cmx, __shfl_xor(cmx, o));
                float n = fmaxf(m, cmx);
                float r = __expf(m - n);
                p = __expf(e - n);
                s_sx[w][lane] = sidx;
                s_ph[w][lane] = (__half)p;
                float qq2 = p;
                #pragma unroll
                for (int o = 32; o > 0; o >>= 1) qq2 += __shfl_xor(qq2, o);
                ssum = ssum * r + qq2;
                __half2 r2 = __half2half2((__half)r);
                #pragma unroll
                for (int k = 0; k < 4; ++k) acc2[k] = __hmul2(acc2[k], r2);
                m = n;
                agg(nch);
            }
        }

        // reduce across the 16 subgroups (offsets 4..32) in packed fp16
        #pragma unroll
        for (int k = 0; k < 4; ++k) {
            acc2[k] = __hadd2(acc2[k], shfl_xor_h2(acc2[k], 4));
            acc2[k] = __hadd2(acc2[k], shfl_xor_h2(acc2[k], 8));
            acc2[k] = __hadd2(acc2[k], shfl_xor_h2(acc2[k], 16));
            acc2[k] = __hadd2(acc2[k], shfl_xor_h2(acc2[k], 32));
        }
        if (g == 0) {
            float inv = (deg > 0) ? 1.f / ssum : 0.f;
            float2 f0 = __half22float2(acc2[0]);
            float2 f1 = __half22float2(acc2[1]);
            float2 f2 = __half22float2(acc2[2]);
            float2 f3 = __half22float2(acc2[3]);
            uint4 o;
            o.x = pkh2(f0.x * inv, f0.y * inv);
            o.y = pkh2(f1.x * inv, f1.y * inv);
            o.z = pkh2(f2.x * inv, f2.y * inv);
            o.w = pkh2(f3.x * inv, f3.y * inv);
            *(uint4*)(out + (size_t)nd * 128 + s * 32 + q * 8) = o;
        }
    }
}

// ---- layer 2 fused attention+aggregate (H=1, D=64) — unchanged from R10 ----
__global__ __launch_bounds__(256) void k_fused2(
    const unsigned* __restrict__ rowdeg, const int* __restrict__ csr_src,
    const __half* __restrict__ h,  // [N,64] fp16
    const float* __restrict__ el,  // [N]
    const float* __restrict__ er,  // [N]
    float* __restrict__ out)       // [N,64] f32
{
    __shared__ int    s_sx[4][64];
    __shared__ __half s_p[4][64];
    const int w = threadIdx.x >> 6;
    int node = (blockIdx.x << 2) + w;
    int lane = threadIdx.x & 63;
    if (node >= N_NODES) return;
    unsigned rd = rowdeg[node];
    int rs = (int)(rd >> 8), deg = (int)(rd & 255u);
    int re = rs + deg;
    const int q = lane & 7, g = lane >> 3;
    float erd = er[node];
    float m, s = 0.f;
    __half2 acc2[4];
    #pragma unroll
    for (int k = 0; k < 4; ++k) acc2[k] = __half2half2((__half)0.f);

    auto agg = [&](int nch) {
        int nit4 = (nch + 31) >> 5;
        for (int t = 0; t < nit4; ++t) {
            int eb = t * 32 + g;
            int sj0 = s_sx[w][eb];
            int sj1 = s_sx[w][eb + 8];
            int sj2 = s_sx[w][eb + 16];
            int sj3 = s_sx[w][eb + 24];
            __half2 a0 = __half2half2(s_p[w][eb]);
            __half2 a1 = __half2half2(s_p[w][eb + 8]);
            __half2 a2 = __half2half2(s_p[w][eb + 16]);
            __half2 a3 = __half2half2(s_p[w][eb + 24]);
            uint4 v0 = *((const uint4*)(h + (size_t)sj0 * 64) + q);
            uint4 v1 = *((const uint4*)(h + (size_t)sj1 * 64) + q);
            uint4 v2 = *((const uint4*)(h + (size_t)sj2 * 64) + q);
            uint4 v3 = *((const uint4*)(h + (size_t)sj3 * 64) + q);
            acc2[0] = __hfma2(*(__half2*)&v0.x, a0, acc2[0]);
            acc2[1] = __hfma2(*(__half2*)&v0.y, a0, acc2[1]);
            acc2[2] = __hfma2(*(__half2*)&v0.z, a0, acc2[2]);
            acc2[3] = __hfma2(*(__half2*)&v0.w, a0, acc2[3]);
            acc2[0] = __hfma2(*(__half2*)&v1.x, a1, acc2[0]);
            acc2[1] = __hfma2(*(__half2*)&v1.y, a1, acc2[1]);
            acc2[2] = __hfma2(*(__half2*)&v1.z, a1, acc2[2]);
            acc2[3] = __hfma2(*(__half2*)&v1.w, a1, acc2[3]);
            acc2[0] = __hfma2(*(__half2*)&v2.x, a2, acc2[0]);
            acc2[1] = __hfma2(*(__half2*)&v2.y, a2, acc2[1]);
            acc2[2] = __hfma2(*(__half2*)&v2.z, a2, acc2[2]);
            acc2[3] = __hfma2(*(__half2*)&v2.w, a2, acc2[3]);
            acc2[0] = __hfma2(*(__half2*)&v3.x, a3, acc2[0]);
            acc2[1] = __hfma2(*(__half2*)&v3.y, a3, acc2[1]);
            acc2[2] = __hfma2(*(__half2*)&v3.z, a3, acc2[2]);
            acc2[3] = __hfma2(*(__half2*)&v3.w, a3, acc2[3]);
        }
    };

    if (re > rs) {
        int nch = min(64, re - rs);
        int sidx = 0;
        float e = -INFINITY;
        if (lane < nch) {
            sidx = csr_src[rs + lane];
            e = el[sidx] + erd;
            e = e >= 0.f ? e : 0.2f * e;
        }
        float c = e;
        #pragma unroll
        for (int o = 32; o > 0; o >>= 1) c = fmaxf(c, __shfl_xor(c, o));
        m = c;
        float p = __expf(e - m);
        s_sx[w][lane] = sidx;
        s_p[w][lane] = (__half)p;
        float qq = p;
        #pragma unroll
        for (int o = 32; o > 0; o >>= 1) qq += __shfl_xor(qq, o);
        s = qq;
        agg(nch);

        for (int base = rs + 64; base < re; base += 64) {
            nch = min(64, re - base);
            sidx = 0;
            e = -INFINITY;
            if (lane < nch) {
                sidx = csr_src[base + lane];
                e = el[sidx] + erd;
                e = e >= 0.f ? e : 0.2f * e;
            }
            c = e;
            #pragma unroll
            for (int o = 32; o > 0; o >>= 1) c = fmaxf(c, __shfl_xor(c, o));
            float n = fmaxf(m, c);
            float r = __expf(m - n);
            p = __expf(e - n);
            s_sx[w][lane] = sidx;
            s_p[w][lane] = (__half)p;
            float qq2 = p;
            #pragma unroll
            for (int o = 32; o > 0; o >>= 1) qq2 += __shfl_xor(qq2, o);
            s = s * r + qq2;
            __half2 r2 = __half2half2((__half)r);
            #pragma unroll
            for (int k = 0; k < 4; ++k) acc2[k] = __hmul2(acc2[k], r2);
            m = n;
            agg(nch);
        }
    }

    float inv = (re > rs) ? 1.f / s : 0.f;
    float acc[8];
    #pragma unroll
    for (int k = 0; k < 4; ++k) {
        float2 f = __half22float2(acc2[k]);
        acc[2*k] = f.x * inv; acc[2*k+1] = f.y * inv;
    }
    #pragma unroll
    for (int k = 0; k < 8; ++k) {
        acc[k] += __shfl_xor(acc[k], 8);
        acc[k] += __shfl_xor(acc[k], 16);
        acc[k] += __shfl_xor(acc[k], 32);
    }
    if (g == 0) {
        float* op = out + (size_t)node * 64 + q * 8;
        *(float4*)(op)     = make_float4(acc[0], acc[1], acc[2], acc[3]);
        *(float4*)(op + 4) = make_float4(acc[4], acc[5], acc[6], acc[7]);
    }
}

extern "C" void kernel_launch(void* const* d_in, const int* in_sizes, int n_in,
                              void* d_out, int out_size, void* d_ws, size_t ws_size,
                              hipStream_t stream) {
    const float* x   = (const float*)d_in[0];
    const int*   src = (const int*)d_in[1];
    const int*   dst = (const int*)d_in[2];
    const float* W1  = (const float*)d_in[3];
    const float* al1 = (const float*)d_in[4];
    const float* ar1 = (const float*)d_in[5];
    const float* W2  = (const float*)d_in[6];
    const float* al2 = (const float*)d_in[7];
    const float* ar2 = (const float*)d_in[8];
    float* out = (float*)d_out;

    char* base = (char*)d_ws;
    _Float16* h1s  = (_Float16*)base; base += (size_t)N_NODES * 128 * 2;  // [4][N][32]
    __half*   out1 = (__half*)base;   base += (size_t)N_NODES * 128 * 2;  // row-major
    float*  el1  = (float*)base;    base += (size_t)N_NODES * 4 * 4;
    float*  er1  = (float*)base;    base += (size_t)N_NODES * 4 * 4;
    unsigned* rowdeg = (unsigned*)base; base += (size_t)100004 * 4;
    int* cursor  = (int*)base;      base += 512 * 4;
    int* csr_src = (int*)base;      base += (size_t)NB * BPAD * 4;
    unsigned* pairs = (unsigned*)base; base += (size_t)NB * BPAD * 4;
    // layer-2 buffers alias h1s region (dead after k_fused1):
    __half* h2   = (__half*)h1s;
    float*  el2  = (float*)((char*)h1s + (size_t)N_NODES * 64 * 2);
    float*  er2  = el2 + N_NODES;

    // ---- CSR build (place) ----
    hipMemsetAsync(cursor, 0, NB * sizeof(int), stream);
    k_place<<<NBLK, 256, 0, stream>>>(src, dst, cursor, pairs);

    // ---- merged: csr scatter (391 blocks) || layer-1 GEMM (1563 blocks) ----
    k_mix1<<<NB + GB1, 256, 0, stream>>>(x, W1, al1, ar1, h1s, el1, er1,
                                         pairs, cursor, rowdeg, csr_src);

    // ---- layer 1 fused (sliced, XCD-pinned heads) ----
    k_fused1<<<(N_NODES / 8) * 4, 256, 0, stream>>>(rowdeg, csr_src, h1s,
                                                    el1, er1, out1);

    // ---- layer 2 ----
    k_gemm2<<<(N_NODES + 63) / 64, 256, 0, stream>>>(out1, W2, al2, ar2, h2, el2, er2);
    k_fused2<<<(N_NODES + 3) / 4, 256, 0, stream>>>(rowdeg, csr_src, h2, el2, er2, out);
}

// Round 12
// 224.451 us; speedup vs baseline: 1.3181x; 1.3181x over previous
//
#include <hip/hip_runtime.h>
#include <hip/hip_fp16.h>

#define N_NODES 100000
#define N_EDGES 1600000
#define NB 391            // buckets = dst>>8 (256 nodes each)
#define CHUNK 6250        // N_EDGES / 256 exactly
#define NBLK 256          // partition blocks
#define BPAD 4736         // padded per-bucket stride
#define GB1 1563          // gemm1 blocks = ceil(N/64)

typedef _Float16 half8 __attribute__((ext_vector_type(8)));
typedef float f32x4 __attribute__((ext_vector_type(4)));

static __device__ __forceinline__ unsigned pkh2(float a, float b) {
    __half2 t = __floats2half2_rn(a, b);
    return *(unsigned*)&t;
}

// ============ gemm1 body (MFMA): h1 = x @ W1, row-major h output ============
static __device__ void gemm1_body(
    int blk, char* smem,
    const float* __restrict__ x, const float* __restrict__ W,
    const float* __restrict__ al, const float* __restrict__ ar,
    __half* __restrict__ h, float* __restrict__ el, float* __restrict__ er)
{
    _Float16* Wt = (_Float16*)smem;            // [col][k] 128x136
    _Float16* xs = (_Float16*)(smem + 34816);  // [row][k] 64x136, then C
    const int tid = threadIdx.x;
    const int n0 = blk * 64;

    #pragma unroll
    for (int pass = 0; pass < 16; ++pass) {
        int k  = (tid >> 5) + pass * 8;
        int c4 = (tid & 31) * 4;
        float4 w = *(const float4*)(W + (size_t)k * 128 + c4);
        Wt[(c4 + 0) * 136 + k] = (_Float16)w.x;
        Wt[(c4 + 1) * 136 + k] = (_Float16)w.y;
        Wt[(c4 + 2) * 136 + k] = (_Float16)w.z;
        Wt[(c4 + 3) * 136 + k] = (_Float16)w.w;
    }
    {
        int row = tid >> 2, kq = (tid & 3) * 32;
        int n = n0 + row;
        _Float16* d = xs + row * 136 + kq;
        if (n < N_NODES) {
            const float* xp = x + (size_t)n * 128 + kq;
            #pragma unroll
            for (int j = 0; j < 8; ++j) {
                float4 v = *(const float4*)(xp + j * 4);
                d[j*4+0] = (_Float16)v.x; d[j*4+1] = (_Float16)v.y;
                d[j*4+2] = (_Float16)v.z; d[j*4+3] = (_Float16)v.w;
            }
        } else {
            #pragma unroll
            for (int j = 0; j < 32; ++j) d[j] = (_Float16)0.f;
        }
    }
    __syncthreads();

    const int wv = tid >> 6, l = tid & 63;
    const int r0 = wv * 16;
    const int lc = l & 15, lk = l >> 4;

    half8 afr[4];
    #pragma unroll
    for (int ks = 0; ks < 4; ++ks)
        afr[ks] = *(const half8*)(xs + (r0 + lc) * 136 + ks * 32 + lk * 8);
    __syncthreads();

    float eh_l[4][4], eh_r[4][4];
    #pragma unroll
    for (int hd = 0; hd < 4; ++hd)
        #pragma unroll
        for (int i = 0; i < 4; ++i) { eh_l[hd][i] = 0.f; eh_r[hd][i] = 0.f; }

    f32x4 accs[8];
    #pragma unroll
    for (int ct = 0; ct < 8; ++ct) {
        f32x4 acc = {0.f, 0.f, 0.f, 0.f};
        #pragma unroll
        for (int ks = 0; ks < 4; ++ks) {
            half8 b = *(const half8*)(Wt + (ct * 16 + lc) * 136 + ks * 32 + lk * 8);
            acc = __builtin_amdgcn_mfma_f32_16x16x32_f16(afr[ks], b, acc, 0, 0, 0);
        }
        accs[ct] = acc;
        float a_l = al[ct * 16 + lc], a_r = ar[ct * 16 + lc];
        #pragma unroll
        for (int i = 0; i < 4; ++i) {
            eh_l[ct >> 1][i] = fmaf(acc[i], a_l, eh_l[ct >> 1][i]);
            eh_r[ct >> 1][i] = fmaf(acc[i], a_r, eh_r[ct >> 1][i]);
        }
    }

    #pragma unroll
    for (int ct = 0; ct < 8; ++ct)
        #pragma unroll
        for (int i = 0; i < 4; ++i)
            xs[(r0 + lk * 4 + i) * 136 + ct * 16 + lc] = (_Float16)accs[ct][i];

    #pragma unroll
    for (int hd = 0; hd < 4; ++hd)
        #pragma unroll
        for (int i = 0; i < 4; ++i) {
            float v = eh_l[hd][i];
            v += __shfl_xor(v, 1); v += __shfl_xor(v, 2);
            v += __shfl_xor(v, 4); v += __shfl_xor(v, 8);
            eh_l[hd][i] = v;
            float u = eh_r[hd][i];
            u += __shfl_xor(u, 1); u += __shfl_xor(u, 2);
            u += __shfl_xor(u, 4); u += __shfl_xor(u, 8);
            eh_r[hd][i] = u;
        }
    if (lc == 0) {
        #pragma unroll
        for (int i = 0; i < 4; ++i) {
            int n = n0 + r0 + lk * 4 + i;
            if (n < N_NODES) {
                #pragma unroll
                for (int hd = 0; hd < 4; ++hd) {
                    el[n * 4 + hd] = eh_l[hd][i];
                    er[n * 4 + hd] = eh_r[hd][i];
                }
            }
        }
    }
    __syncthreads();
    {
        int row = tid >> 2, kq = (tid & 3) * 32;
        int n = n0 + row;
        if (n < N_NODES) {
            #pragma unroll
            for (int j = 0; j < 4; ++j)
                *(uint4*)(h + (size_t)n * 128 + kq + j * 8) =
                    *(const uint4*)(xs + row * 136 + kq + j * 8);
        }
    }
}

// ======================= csr body (one block per bucket) ====================
static __device__ void csr_body(
    int b, char* smem,
    const unsigned* __restrict__ pairs, const int* __restrict__ cursor,
    unsigned* __restrict__ rowdeg, int* __restrict__ csr_src)
{
    int* cnt = (int*)smem;
    int* exc = (int*)(smem + 1024);
    const int tid = threadIdx.x;
    cnt[tid] = 0;
    __syncthreads();
    int beg = b * BPAD;
    int end = beg + cursor[b];
    for (int i = beg + tid; i < end; i += 256)
        atomicAdd(&cnt[pairs[i] >> 17], 1);
    __syncthreads();
    int v = cnt[tid];
    exc[tid] = v;
    __syncthreads();
    for (int o = 1; o < 256; o <<= 1) {
        int t = (tid >= o) ? exc[tid - o] : 0;
        __syncthreads();
        exc[tid] += t;
        __syncthreads();
    }
    int excl = exc[tid] - v;
    int node = b * 256 + tid;
    if (node < N_NODES)
        rowdeg[node] = ((unsigned)(beg + excl) << 8) | (unsigned)v;
    __syncthreads();
    exc[tid] = beg + excl;
    cnt[tid] = 0;
    __syncthreads();
    for (int i = beg + tid; i < end; i += 256) {
        unsigned e = pairs[i];
        int dl = (int)(e >> 17);
        int r = atomicAdd(&cnt[dl], 1);
        csr_src[exc[dl] + r] = (int)(e & 0x1FFFFu);
    }
}

// ---- merged launch: csr buckets (blocks 0..NB) + gemm1 (blocks NB..NB+GB1) --
__global__ __launch_bounds__(256) void k_mix1(
    const float* __restrict__ x, const float* __restrict__ W,
    const float* __restrict__ al, const float* __restrict__ ar,
    __half* __restrict__ h, float* __restrict__ el, float* __restrict__ er,
    const unsigned* __restrict__ pairs, const int* __restrict__ cursor,
    unsigned* __restrict__ rowdeg, int* __restrict__ csr_src)
{
    __shared__ __align__(16) char smem[52224];
    if (blockIdx.x < NB)
        csr_body(blockIdx.x, smem, pairs, cursor, rowdeg, csr_src);
    else
        gemm1_body(blockIdx.x - NB, smem, x, W, al, ar, h, el, er);
}

// ===== layer 2 GEMM (MFMA): h2 = selu(out1) @ W2 (K=128, N=64) =====
__global__ __launch_bounds__(256) void k_gemm2(
    const __half* __restrict__ in, const float* __restrict__ W,
    const float* __restrict__ al, const float* __restrict__ ar,
    __half* __restrict__ h, float* __restrict__ el, float* __restrict__ er)
{
    __shared__ _Float16 Wt[64 * 136];   // [col][k]
    __shared__ _Float16 xs[64 * 136];   // [row][k], then C
    const int tid = threadIdx.x;
    const int n0 = blockIdx.x * 64;
    const float SC = 1.0507009873554805f;
    const float AL = 1.6732632423543772f;

    #pragma unroll
    for (int pass = 0; pass < 8; ++pass) {
        int k  = (tid >> 4) + pass * 16;
        int c4 = (tid & 15) * 4;
        float4 w = *(const float4*)(W + (size_t)k * 64 + c4);
        Wt[(c4 + 0) * 136 + k] = (_Float16)w.x;
        Wt[(c4 + 1) * 136 + k] = (_Float16)w.y;
        Wt[(c4 + 2) * 136 + k] = (_Float16)w.z;
        Wt[(c4 + 3) * 136 + k] = (_Float16)w.w;
    }
    {
        int row = tid >> 2, kq = (tid & 3) * 32;
        int n = n0 + row;
        _Float16* d = xs + row * 136 + kq;
        if (n < N_NODES) {
            const __half* ip = in + (size_t)n * 128 + kq;
            #pragma unroll
            for (int j = 0; j < 8; ++j) {
                uint2 u = *(const uint2*)(ip + j * 4);
                float2 f01 = __half22float2(*(__half2*)&u.x);
                float2 f23 = __half22float2(*(__half2*)&u.y);
                float v0 = f01.x > 0.f ? SC * f01.x : SC * AL * (__expf(f01.x) - 1.f);
                float v1 = f01.y > 0.f ? SC * f01.y : SC * AL * (__expf(f01.y) - 1.f);
                float v2 = f23.x > 0.f ? SC * f23.x : SC * AL * (__expf(f23.x) - 1.f);
                float v3 = f23.y > 0.f ? SC * f23.y : SC * AL * (__expf(f23.y) - 1.f);
                d[j*4+0] = (_Float16)v0; d[j*4+1] = (_Float16)v1;
                d[j*4+2] = (_Float16)v2; d[j*4+3] = (_Float16)v3;
            }
        } else {
            #pragma unroll
            for (int j = 0; j < 32; ++j) d[j] = (_Float16)0.f;
        }
    }
    __syncthreads();

    const int wv = tid >> 6, l = tid & 63;
    const int r0 = wv * 16;
    const int lc = l & 15, lk = l >> 4;

    half8 afr[4];
    #pragma unroll
    for (int ks = 0; ks < 4; ++ks)
        afr[ks] = *(const half8*)(xs + (r0 + lc) * 136 + ks * 32 + lk * 8);
    __syncthreads();

    float pl[4], pr[4];
    #pragma unroll
    for (int i = 0; i < 4; ++i) { pl[i] = 0.f; pr[i] = 0.f; }

    f32x4 accs[4];
    #pragma unroll
    for (int ct = 0; ct < 4; ++ct) {
        f32x4 acc = {0.f, 0.f, 0.f, 0.f};
        #pragma unroll
        for (int ks = 0; ks < 4; ++ks) {
            half8 b = *(const half8*)(Wt + (ct * 16 + lc) * 136 + ks * 32 + lk * 8);
            acc = __builtin_amdgcn_mfma_f32_16x16x32_f16(afr[ks], b, acc, 0, 0, 0);
        }
        accs[ct] = acc;
        float a_l = al[ct * 16 + lc], a_r = ar[ct * 16 + lc];
        #pragma unroll
        for (int i = 0; i < 4; ++i) {
            pl[i] = fmaf(acc[i], a_l, pl[i]);
            pr[i] = fmaf(acc[i], a_r, pr[i]);
        }
    }

    #pragma unroll
    for (int ct = 0; ct < 4; ++ct)
        #pragma unroll
        for (int i = 0; i < 4; ++i)
            xs[(r0 + lk * 4 + i) * 136 + ct * 16 + lc] = (_Float16)accs[ct][i];

    #pragma unroll
    for (int i = 0; i < 4; ++i) {
        float v = pl[i];
        v += __shfl_xor(v, 1); v += __shfl_xor(v, 2);
        v += __shfl_xor(v, 4); v += __shfl_xor(v, 8);
        pl[i] = v;
        float u = pr[i];
        u += __shfl_xor(u, 1); u += __shfl_xor(u, 2);
        u += __shfl_xor(u, 4); u += __shfl_xor(u, 8);
        pr[i] = u;
    }
    if (lc == 0) {
        #pragma unroll
        for (int i = 0; i < 4; ++i) {
            int n = n0 + r0 + lk * 4 + i;
            if (n < N_NODES) { el[n] = pl[i]; er[n] = pr[i]; }
        }
    }
    __syncthreads();
    {
        int row = tid >> 2, kq = (tid & 3) * 16;
        int n = n0 + row;
        if (n < N_NODES) {
            #pragma unroll
            for (int j = 0; j < 2; ++j)
                *(uint4*)(h + (size_t)n * 64 + kq + j * 8) =
                    *(const uint4*)(xs + row * 136 + kq + j * 8);
        }
    }
}

// ---- place: LDS bucket histogram -> bulk cursor reservation -> padded write ----
__global__ __launch_bounds__(256) void k_place(
    const int* __restrict__ src, const int* __restrict__ dst,
    int* __restrict__ cursor, unsigned* __restrict__ pairs)
{
    __shared__ int cnt[NB], basev[NB];
    const int tid = threadIdx.x;
    for (int j = tid; j < NB; j += 256) cnt[j] = 0;
    __syncthreads();
    int beg = blockIdx.x * CHUNK, end = beg + CHUNK;
    for (int i = beg + tid; i < end; i += 256)
        atomicAdd(&cnt[dst[i] >> 8], 1);
    __syncthreads();
    for (int j = tid; j < NB; j += 256)
        basev[j] = cnt[j] ? atomicAdd(&cursor[j], cnt[j]) : 0;
    __syncthreads();
    for (int j = tid; j < NB; j += 256) cnt[j] = 0;
    __syncthreads();
    for (int i = beg + tid; i < end; i += 256) {
        int d = dst[i];
        int b = d >> 8;
        int r = atomicAdd(&cnt[b], 1);
        pairs[(size_t)b * BPAD + basev[b] + r] =
            ((unsigned)(d & 255) << 17) | (unsigned)src[i];
    }
}

// ---- layer 1 fused attention+aggregate: one wave per node (R10 version) ----
__global__ __launch_bounds__(256) void k_fused1(
    const unsigned* __restrict__ rowdeg, const int* __restrict__ csr_src,
    const __half* __restrict__ h,  // [N,128] fp16
    const float* __restrict__ el,  // [N,4]
    const float* __restrict__ er,  // [N,4]
    __half* __restrict__ out)      // [N,128] fp16
{
    __shared__ int    s_sx[4][64];
    __shared__ __half s_p[4][64][4];
    const int w = threadIdx.x >> 6;
    int node = (blockIdx.x << 2) + w;
    int lane = threadIdx.x & 63;
    if (node >= N_NODES) return;
    unsigned rd = rowdeg[node];
    int rs = (int)(rd >> 8), deg = (int)(rd & 255u);
    int re = rs + deg;
    const int q = lane & 15, g = lane >> 4;
    const int hq = q >> 2;
    float4 erd = ((const float4*)er)[node];
    float m0, m1, m2, m3;
    float s0 = 0.f, s1 = 0.f, s2 = 0.f, s3 = 0.f;
    __half2 acc2[4];
    #pragma unroll
    for (int k = 0; k < 4; ++k) acc2[k] = __half2half2((__half)0.f);

    auto agg = [&](int nch) {
        int nit4 = (nch + 15) >> 4;
        for (int t = 0; t < nit4; ++t) {
            int eb = t * 16 + g;
            int sj0 = s_sx[w][eb];
            int sj1 = s_sx[w][eb + 4];
            int sj2 = s_sx[w][eb + 8];
            int sj3 = s_sx[w][eb + 12];
            __half2 a0 = __half2half2(s_p[w][eb][hq]);
            __half2 a1 = __half2half2(s_p[w][eb + 4][hq]);
            __half2 a2 = __half2half2(s_p[w][eb + 8][hq]);
            __half2 a3 = __half2half2(s_p[w][eb + 12][hq]);
            uint4 v0 = *((const uint4*)(h + (size_t)sj0 * 128) + q);
            uint4 v1 = *((const uint4*)(h + (size_t)sj1 * 128) + q);
            uint4 v2 = *((const uint4*)(h + (size_t)sj2 * 128) + q);
            uint4 v3 = *((const uint4*)(h + (size_t)sj3 * 128) + q);
            acc2[0] = __hfma2(*(__half2*)&v0.x, a0, acc2[0]);
            acc2[1] = __hfma2(*(__half2*)&v0.y, a0, acc2[1]);
            acc2[2] = __hfma2(*(__half2*)&v0.z, a0, acc2[2]);
            acc2[3] = __hfma2(*(__half2*)&v0.w, a0, acc2[3]);
            acc2[0] = __hfma2(*(__half2*)&v1.x, a1, acc2[0]);
            acc2[1] = __hfma2(*(__half2*)&v1.y, a1, acc2[1]);
            acc2[2] = __hfma2(*(__half2*)&v1.z, a1, acc2[2]);
            acc2[3] = __hfma2(*(__half2*)&v1.w, a1, acc2[3]);
            acc2[0] = __hfma2(*(__half2*)&v2.x, a2, acc2[0]);
            acc2[1] = __hfma2(*(__half2*)&v2.y, a2, acc2[1]);
            acc2[2] = __hfma2(*(__half2*)&v2.z, a2, acc2[2]);
            acc2[3] = __hfma2(*(__half2*)&v2.w, a2, acc2[3]);
            acc2[0] = __hfma2(*(__half2*)&v3.x, a3, acc2[0]);
            acc2[1] = __hfma2(*(__half2*)&v3.y, a3, acc2[1]);
            acc2[2] = __hfma2(*(__half2*)&v3.z, a3, acc2[2]);
            acc2[3] = __hfma2(*(__half2*)&v3.w, a3, acc2[3]);
        }
    };

    if (re > rs) {
        int nch = min(64, re - rs);
        int sidx = 0;
        float e0 = -INFINITY, e1 = -INFINITY, e2 = -INFINITY, e3 = -INFINITY;
        if (lane < nch) {
            sidx = csr_src[rs + lane];
            float4 l4 = ((const float4*)el)[sidx];
            e0 = l4.x + erd.x; e0 = e0 >= 0.f ? e0 : 0.2f * e0;
            e1 = l4.y + erd.y; e1 = e1 >= 0.f ? e1 : 0.2f * e1;
            e2 = l4.z + erd.z; e2 = e2 >= 0.f ? e2 : 0.2f * e2;
            e3 = l4.w + erd.w; e3 = e3 >= 0.f ? e3 : 0.2f * e3;
        }
        float c0 = e0, c1 = e1, c2 = e2, c3 = e3;
        #pragma unroll
        for (int o = 32; o > 0; o >>= 1) {
            c0 = fmaxf(c0, __shfl_xor(c0, o));
            c1 = fmaxf(c1, __shfl_xor(c1, o));
            c2 = fmaxf(c2, __shfl_xor(c2, o));
            c3 = fmaxf(c3, __shfl_xor(c3, o));
        }
        m0 = c0; m1 = c1; m2 = c2; m3 = c3;
        float p0 = __expf(e0 - m0), p1 = __expf(e1 - m1);
        float p2 = __expf(e2 - m2), p3 = __expf(e3 - m3);
        s_sx[w][lane] = sidx;
        *(__half2*)&s_p[w][lane][0] = __floats2half2_rn(p0, p1);
        *(__half2*)&s_p[w][lane][2] = __floats2half2_rn(p2, p3);
        float q0 = p0, q1 = p1, q2 = p2, q3 = p3;
        #pragma unroll
        for (int o = 32; o > 0; o >>= 1) {
            q0 += __shfl_xor(q0, o);
            q1 += __shfl_xor(q1, o);
            q2 += __shfl_xor(q2, o);
            q3 += __shfl_xor(q3, o);
        }
        s0 = q0; s1 = q1; s2 = q2; s3 = q3;
        agg(nch);

        // degree > 64 tail (never taken for this graph; kept for correctness)
        for (int base = rs + 64; base < re; base += 64) {
            nch = min(64, re - base);
            sidx = 0;
            e0 = e1 = e2 = e3 = -INFINITY;
            if (lane < nch) {
                sidx = csr_src[base + lane];
                float4 l4 = ((const float4*)el)[sidx];
                e0 = l4.x + erd.x; e0 = e0 >= 0.f ? e0 : 0.2f * e0;
                e1 = l4.y + erd.y; e1 = e1 >= 0.f ? e1 : 0.2f * e1;
                e2 = l4.z + erd.z; e2 = e2 >= 0.f ? e2 : 0.2f * e2;
                e3 = l4.w + erd.w; e3 = e3 >= 0.f ? e3 : 0.2f * e3;
            }
            c0 = e0; c1 = e1; c2 = e2; c3 = e3;
            #pragma unroll
            for (int o = 32; o > 0; o >>= 1) {
                c0 = fmaxf(c0, __shfl_xor(c0, o));
                c1 = fmaxf(c1, __shfl_xor(c1, o));
                c2 = fmaxf(c2, __shfl_xor(c2, o));
                c3 = fmaxf(c3, __shfl_xor(c3, o));
            }
            float n0 = fmaxf(m0, c0), n1 = fmaxf(m1, c1);
            float n2 = fmaxf(m2, c2), n3 = fmaxf(m3, c3);
            float r0 = __expf(m0 - n0), r1 = __expf(m1 - n1);
            float r2 = __expf(m2 - n2), r3 = __expf(m3 - n3);
            p0 = __expf(e0 - n0); p1 = __expf(e1 - n1);
            p2 = __expf(e2 - n2); p3 = __expf(e3 - n3);
            s_sx[w][lane] = sidx;
            *(__half2*)&s_p[w][lane][0] = __floats2half2_rn(p0, p1);
            *(__half2*)&s_p[w][lane][2] = __floats2half2_rn(p2, p3);
            q0 = p0; q1 = p1; q2 = p2; q3 = p3;
            #pragma unroll
            for (int o = 32; o > 0; o >>= 1) {
                q0 += __shfl_xor(q0, o);
                q1 += __shfl_xor(q1, o);
                q2 += __shfl_xor(q2, o);
                q3 += __shfl_xor(q3, o);
            }
            s0 = s0 * r0 + q0; s1 = s1 * r1 + q1;
            s2 = s2 * r2 + q2; s3 = s3 * r3 + q3;
            float rh = hq == 0 ? r0 : hq == 1 ? r1 : hq == 2 ? r2 : r3;
            __half2 rh2 = __half2half2((__half)rh);
            #pragma unroll
            for (int k = 0; k < 4; ++k) acc2[k] = __hmul2(acc2[k], rh2);
            m0 = n0; m1 = n1; m2 = n2; m3 = n3;
            agg(nch);
        }
    }

    float sh = hq == 0 ? s0 : hq == 1 ? s1 : hq == 2 ? s2 : s3;
    float inv = (re > rs) ? 1.f / sh : 0.f;
    float acc[8];
    #pragma unroll
    for (int k = 0; k < 4; ++k) {
        float2 f = __half22float2(acc2[k]);
        acc[2*k] = f.x * inv; acc[2*k+1] = f.y * inv;
    }
    #pragma unroll
    for (int k = 0; k < 8; ++k) {
        acc[k] += __shfl_xor(acc[k], 16);
        acc[k] += __shfl_xor(acc[k], 32);
    }
    if (g == 0) {
        uint4 o;
        o.x = pkh2(acc[0], acc[1]);
        o.y = pkh2(acc[2], acc[3]);
        o.z = pkh2(acc[4], acc[5]);
        o.w = pkh2(acc[6], acc[7]);
        *((uint4*)(out + (size_t)node * 128) + q) = o;
    }
}

// ---- layer 2 fused attention+aggregate (H=1, D=64) ----
__global__ __launch_bounds__(256) void k_fused2(
    const unsigned* __restrict__ rowdeg, const int* __restrict__ csr_src,
    const __half* __restrict__ h,  // [N,64] fp16
    const float* __restrict__ el,  // [N]
    const float* __restrict__ er,  // [N]
    float* __restrict__ out)       // [N,64] f32
{
    __shared__ int    s_sx[4][64];
    __shared__ __half s_p[4][64];
    const int w = threadIdx.x >> 6;
    int node = (blockIdx.x << 2) + w;
    int lane = threadIdx.x & 63;
    if (node >= N_NODES) return;
    unsigned rd = rowdeg[node];
    int rs = (int)(rd >> 8), deg = (int)(rd & 255u);
    int re = rs + deg;
    const int q = lane & 7, g = lane >> 3;
    float erd = er[node];
    float m, s = 0.f;
    __half2 acc2[4];
    #pragma unroll
    for (int k = 0; k < 4; ++k) acc2[k] = __half2half2((__half)0.f);

    auto agg = [&](int nch) {
        int nit4 = (nch + 31) >> 5;
        for (int t = 0; t < nit4; ++t) {
            int eb = t * 32 + g;
            int sj0 = s_sx[w][eb];
            int sj1 = s_sx[w][eb + 8];
            int sj2 = s_sx[w][eb + 16];
            int sj3 = s_sx[w][eb + 24];
            __half2 a0 = __half2half2(s_p[w][eb]);
            __half2 a1 = __half2half2(s_p[w][eb + 8]);
            __half2 a2 = __half2half2(s_p[w][eb + 16]);
            __half2 a3 = __half2half2(s_p[w][eb + 24]);
            uint4 v0 = *((const uint4*)(h + (size_t)sj0 * 64) + q);
            uint4 v1 = *((const uint4*)(h + (size_t)sj1 * 64) + q);
            uint4 v2 = *((const uint4*)(h + (size_t)sj2 * 64) + q);
            uint4 v3 = *((const uint4*)(h + (size_t)sj3 * 64) + q);
            acc2[0] = __hfma2(*(__half2*)&v0.x, a0, acc2[0]);
            acc2[1] = __hfma2(*(__half2*)&v0.y, a0, acc2[1]);
            acc2[2] = __hfma2(*(__half2*)&v0.z, a0, acc2[2]);
            acc2[3] = __hfma2(*(__half2*)&v0.w, a0, acc2[3]);
            acc2[0] = __hfma2(*(__half2*)&v1.x, a1, acc2[0]);
            acc2[1] = __hfma2(*(__half2*)&v1.y, a1, acc2[1]);
            acc2[2] = __hfma2(*(__half2*)&v1.z, a1, acc2[2]);
            acc2[3] = __hfma2(*(__half2*)&v1.w, a1, acc2[3]);
            acc2[0] = __hfma2(*(__half2*)&v2.x, a2, acc2[0]);
            acc2[1] = __hfma2(*(__half2*)&v2.y, a2, acc2[1]);
            acc2[2] = __hfma2(*(__half2*)&v2.z, a2, acc2[2]);
            acc2[3] = __hfma2(*(__half2*)&v2.w, a2, acc2[3]);
            acc2[0] = __hfma2(*(__half2*)&v3.x, a3, acc2[0]);
            acc2[1] = __hfma2(*(__half2*)&v3.y, a3, acc2[1]);
            acc2[2] = __hfma2(*(__half2*)&v3.z, a3, acc2[2]);
            acc2[3] = __hfma2(*(__half2*)&v3.w, a3, acc2[3]);
        }
    };

    if (re > rs) {
        int nch = min(64, re - rs);
        int sidx = 0;
        float e = -INFINITY;
        if (lane < nch) {
            sidx = csr_src[rs + lane];
            e = el[sidx] + erd;
            e = e >= 0.f ? e : 0.2f * e;
        }
        float c = e;
        #pragma unroll
        for (int o = 32; o > 0; o >>= 1) c = fmaxf(c, __shfl_xor(c, o));
        m = c;
        float p = __expf(e - m);
        s_sx[w][lane] = sidx;
        s_p[w][lane] = (__half)p;
        float qq = p;
        #pragma unroll
        for (int o = 32; o > 0; o >>= 1) qq += __shfl_xor(qq, o);
        s = qq;
        agg(nch);

        for (int base = rs + 64; base < re; base += 64) {
            nch = min(64, re - base);
            sidx = 0;
            e = -INFINITY;
            if (lane < nch) {
                sidx = csr_src[base + lane];
                e = el[sidx] + erd;
                e = e >= 0.f ? e : 0.2f * e;
            }
            c = e;
            #pragma unroll
            for (int o = 32; o > 0; o >>= 1) c = fmaxf(c, __shfl_xor(c, o));
            float n = fmaxf(m, c);
            float r = __expf(m - n);
            p = __expf(e - n);
            s_sx[w][lane] = sidx;
            s_p[w][lane] = (__half)p;
            float qq2 = p;
            #pragma unroll
            for (int o = 32; o > 0; o >>= 1) qq2 += __shfl_xor(qq2, o);
            s = s * r + qq2;
            __half2 r2 = __half2half2((__half)r);
            #pragma unroll
            for (int k = 0; k < 4; ++k) acc2[k] = __hmul2(acc2[k], r2);
            m = n;
            agg(nch);
        }
    }

    float inv = (re > rs) ? 1.f / s : 0.f;
    float acc[8];
    #pragma unroll
    for (int k = 0; k < 4; ++k) {
        float2 f = __half22float2(acc2[k]);
        acc[2*k] = f.x * inv; acc[2*k+1] = f.y * inv;
    }
    #pragma unroll
    for (int k = 0; k < 8; ++k) {
        acc[k] += __shfl_xor(acc[k], 8);
        acc[k] += __shfl_xor(acc[k], 16);
        acc[k] += __shfl_xor(acc[k], 32);
    }
    if (g == 0) {
        float* op = out + (size_t)node * 64 + q * 8;
        *(float4*)(op)     = make_float4(acc[0], acc[1], acc[2], acc[3]);
        *(float4*)(op + 4) = make_float4(acc[4], acc[5], acc[6], acc[7]);
    }
}

extern "C" void kernel_launch(void* const* d_in, const int* in_sizes, int n_in,
                              void* d_out, int out_size, void* d_ws, size_t ws_size,
                              hipStream_t stream) {
    const float* x   = (const float*)d_in[0];
    const int*   src = (const int*)d_in[1];
    const int*   dst = (const int*)d_in[2];
    const float* W1  = (const float*)d_in[3];
    const float* al1 = (const float*)d_in[4];
    const float* ar1 = (const float*)d_in[5];
    const float* W2  = (const float*)d_in[6];
    const float* al2 = (const float*)d_in[7];
    const float* ar2 = (const float*)d_in[8];
    float* out = (float*)d_out;

    char* base = (char*)d_ws;
    __half* h1   = (__half*)base;   base += (size_t)N_NODES * 128 * 2;
    __half* out1 = (__half*)base;   base += (size_t)N_NODES * 128 * 2;
    float*  el1  = (float*)base;    base += (size_t)N_NODES * 4 * 4;
    float*  er1  = (float*)base;    base += (size_t)N_NODES * 4 * 4;
    unsigned* rowdeg = (unsigned*)base; base += (size_t)100004 * 4;
    int* cursor  = (int*)base;      base += 512 * 4;
    int* csr_src = (int*)base;      base += (size_t)NB * BPAD * 4;
    unsigned* pairs = (unsigned*)base; base += (size_t)NB * BPAD * 4;
    // layer-2 buffers alias h1 region (dead after k_fused1):
    __half* h2   = h1;
    float*  el2  = (float*)((char*)h1 + (size_t)N_NODES * 64 * 2);
    float*  er2  = el2 + N_NODES;

    // ---- CSR build (place) ----
    hipMemsetAsync(cursor, 0, NB * sizeof(int), stream);
    k_place<<<NBLK, 256, 0, stream>>>(src, dst, cursor, pairs);

    // ---- merged: csr scatter (391 blocks) || layer-1 GEMM (1563 blocks) ----
    k_mix1<<<NB + GB1, 256, 0, stream>>>(x, W1, al1, ar1, h1, el1, er1,
                                         pairs, cursor, rowdeg, csr_src);

    // ---- layer 1 fused ----
    k_fused1<<<(N_NODES + 3) / 4, 256, 0, stream>>>(rowdeg, csr_src, h1, el1, er1, out1);

    // ---- layer 2 ----
    k_gemm2<<<(N_NODES + 63) / 64, 256, 0, stream>>>(out1, W2, al2, ar2, h2, el2, er2);
    k_fused2<<<(N_NODES + 3) / 4, 256, 0, stream>>>(rowdeg, csr_src, h2, el2, er2, out);
}